// Round 3
// baseline (86.121 us; speedup 1.0000x reference)
//
#include <hip/hip_runtime.h>
#include <hip/hip_bf16.h>

#define NBATCH 4
#define NNODE  20000
#define NF     128
#define NK     16
#define BM     32
#define NROWS  (NBATCH * NNODE)   // 80000
#define NBLK   (NROWS / BM)       // 2500
#define WTF_BYTES 65536           // 8c x 8s x 64lane x 16B fragment-permuted weights
#define XB16_OFF  WTF_BYTES       // bf16 x starts here in ws (20.48 MB)

typedef __attribute__((ext_vector_type(8))) short bf16x8_t;
typedef __attribute__((ext_vector_type(4))) float f32x4_t;

__device__ __forceinline__ unsigned short f2bf(float f) {
  unsigned int u = __float_as_uint(f);
  u += 0x7fffu + ((u >> 16) & 1u);
  return (unsigned short)(u >> 16);
}

// byte offset into sA: [row][512B], XOR-swizzled (both write & read sides)
__device__ __forceinline__ int swz(int row, int kbyte) {
  return (row << 9) + (kbyte ^ ((row & 31) << 4));
}

// ---------------- prep: x f32->bf16, weights -> fragment-permuted bf16 ----
__global__ __launch_bounds__(256) void sage_prep_kernel(
    const float* __restrict__ x, const float* __restrict__ Wself,
    const float* __restrict__ Wnei, unsigned char* __restrict__ ws)
{
  const int bid = blockIdx.x;
  const int tid = threadIdx.x;
  if (bid < 2048) {
    const float4* xv = reinterpret_cast<const float4*>(x);
    uint2* xb = reinterpret_cast<uint2*>(ws + XB16_OFF);
    const int total = NROWS * NF / 4;  // 2,560,000
    for (int c = bid * 256 + tid; c < total; c += 2048 * 256) {
      const float4 v = xv[c];
      uint2 p;
      p.x = (unsigned int)f2bf(v.x) | ((unsigned int)f2bf(v.y) << 16);
      p.y = (unsigned int)f2bf(v.z) | ((unsigned int)f2bf(v.w) << 16);
      xb[c] = p;
    }
  } else {
    // fragment-permuted stacked W^T: ft = (c*8+s)*64 + lane, 16B per ft
    const int ft = (bid - 2048) * 256 + tid;   // 0..4095
    const int c = ft >> 9;
    const int s = (ft >> 6) & 7;
    const int l = ft & 63;
    const int col = c * 16 + (l & 15);
    const int k0 = s * 32 + ((l >> 4) << 3);
    unsigned int w[4];
#pragma unroll
    for (int jj = 0; jj < 4; ++jj) {
      const int ka = k0 + jj * 2, kb = k0 + jj * 2 + 1;
      const float va = (ka < NF) ? Wself[ka * NF + col] : Wnei[(ka - NF) * NF + col];
      const float vb = (kb < NF) ? Wself[kb * NF + col] : Wnei[(kb - NF) * NF + col];
      w[jj] = (unsigned int)f2bf(va) | ((unsigned int)f2bf(vb) << 16);
    }
    *reinterpret_cast<uint4*>(ws + (size_t)ft * 16) = make_uint4(w[0], w[1], w[2], w[3]);
  }
}

// ---------------- fused gather + stacked GEMM ----------------------------
__global__ __launch_bounds__(256, 8) void sage_fused_kernel(
    const unsigned char* __restrict__ ws, const int* __restrict__ adj,
    const float* __restrict__ bself, const float* __restrict__ bnei,
    float* __restrict__ out)
{
  __shared__ __align__(16) unsigned char sA[BM * 512];  // 16 KB

  const int tid  = threadIdx.x;
  const int lane = tid & 63;
  const int wid  = tid >> 6;

  // bijective XCD-chunked swizzle: nwg=2500, q=312, r=4
  const int orig = blockIdx.x;
  const int xcd = orig & 7, i = orig >> 3;
  const int q = NBLK / 8, r = NBLK % 8;
  const int bid = (xcd < r ? xcd * (q + 1) : r * (q + 1) + (xcd - r) * q) + i;
  const int row0 = bid * BM;

  const unsigned char* xb16 = ws + XB16_OFF;

  // ---- stage x tile (k-bytes [0,256) of sA), coalesced 16B chunks
  {
    const int kb = (tid & 15) * 16;
#pragma unroll
    for (int it = 0; it < 2; ++it) {
      const int rr = it * 16 + (tid >> 4);
      const uint4 v = *reinterpret_cast<const uint4*>(
          xb16 + (size_t)(row0 + rr) * 256 + kb);
      *reinterpret_cast<uint4*>(sA + swz(rr, kb)) = v;
    }
  }

  // ---- gather + mean (k-bytes [256,512)): two 128B feature halves
  // (all co-resident blocks do half 0 first -> 2.56MB/XCD working set, L2-fit)
  {
    const int fh   = (lane & 7) * 16;   // byte offset within the 128B half
    const int rsub = lane >> 3;         // 0..7 row within wave's 8-row group
    const int rr   = wid * 8 + rsub;
    const int gr   = row0 + rr;
    const int b    = gr / NNODE;
    const unsigned char* xbb = xb16 + (size_t)b * NNODE * 256;
    const int4* a4 = reinterpret_cast<const int4*>(adj + (size_t)gr * NK);

    int idx[16];
#pragma unroll
    for (int kk = 0; kk < 4; ++kk) {
      const int4 t = a4[kk];
      idx[kk * 4 + 0] = t.x; idx[kk * 4 + 1] = t.y;
      idx[kk * 4 + 2] = t.z; idx[kk * 4 + 3] = t.w;
    }

#pragma unroll
    for (int h = 0; h < 2; ++h) {
      const int off = h * 128 + fh;
      uint4 v[16];
#pragma unroll
      for (int k = 0; k < 16; ++k)
        v[k] = *reinterpret_cast<const uint4*>(xbb + (size_t)idx[k] * 256 + off);
      float a0=0,a1=0,a2=0,a3=0,a4f=0,a5=0,a6=0,a7=0;
#pragma unroll
      for (int k = 0; k < 16; ++k) {
        a0  += __uint_as_float(v[k].x << 16);
        a1  += __uint_as_float(v[k].x & 0xffff0000u);
        a2  += __uint_as_float(v[k].y << 16);
        a3  += __uint_as_float(v[k].y & 0xffff0000u);
        a4f += __uint_as_float(v[k].z << 16);
        a5  += __uint_as_float(v[k].z & 0xffff0000u);
        a6  += __uint_as_float(v[k].w << 16);
        a7  += __uint_as_float(v[k].w & 0xffff0000u);
      }
      const float sc = 1.f / 16.f;
      uint4 p;
      p.x = (unsigned int)f2bf(a0*sc)  | ((unsigned int)f2bf(a1*sc) << 16);
      p.y = (unsigned int)f2bf(a2*sc)  | ((unsigned int)f2bf(a3*sc) << 16);
      p.z = (unsigned int)f2bf(a4f*sc) | ((unsigned int)f2bf(a5*sc) << 16);
      p.w = (unsigned int)f2bf(a6*sc)  | ((unsigned int)f2bf(a7*sc) << 16);
      *reinterpret_cast<uint4*>(sA + swz(rr, 256 + off)) = p;
    }
  }

  __syncthreads();

  // ---- MFMA: wave w -> rows (w&1)*16..+16, cols (w>>1)*64..+64
  const int frow = lane & 15;
  const int kgrp = lane >> 4;
  const int mrow = (wid & 1) * 16;
  const int cb   = wid >> 1;

  f32x4_t acc[4];
#pragma unroll
  for (int c = 0; c < 4; ++c) acc[c] = (f32x4_t){0.f, 0.f, 0.f, 0.f};

  bf16x8_t afr[8];
#pragma unroll
  for (int s = 0; s < 8; ++s) {
    const int kb = s * 64 + kgrp * 16;
    afr[s] = *reinterpret_cast<const bf16x8_t*>(sA + swz(mrow + frow, kb));
  }

  const bf16x8_t* wtf = reinterpret_cast<const bf16x8_t*>(ws);
#pragma unroll
  for (int c = 0; c < 4; ++c) {
    const int gc = cb * 4 + c;
#pragma unroll
    for (int s = 0; s < 8; ++s) {
      const bf16x8_t bfr = wtf[(gc * 8 + s) * 64 + lane];
      acc[c] = __builtin_amdgcn_mfma_f32_16x16x32_bf16(afr[s], bfr, acc[c], 0, 0, 0);
    }
  }

  // ---- epilogue: bias + relu; C/D: col=lane&15, row=(lane>>4)*4+reg
#pragma unroll
  for (int c = 0; c < 4; ++c) {
    const int gc  = cb * 4 + c;
    const int col = gc * 16 + frow;
    const float bias = bself[col] + bnei[col];
#pragma unroll
    for (int j = 0; j < 4; ++j) {
      const int rr = mrow + kgrp * 4 + j;
      const float v = fmaxf(acc[c][j] + bias, 0.f);
      __builtin_nontemporal_store(v, &out[(size_t)(row0 + rr) * NF + col]);
    }
  }
}

extern "C" void kernel_launch(void* const* d_in, const int* in_sizes, int n_in,
                              void* d_out, int out_size, void* d_ws, size_t ws_size,
                              hipStream_t stream) {
  const float* x     = (const float*)d_in[0];
  const int*   adj   = (const int*)d_in[1];
  const float* Wself = (const float*)d_in[2];
  const float* bself = (const float*)d_in[3];
  const float* Wnei  = (const float*)d_in[4];
  const float* bnei  = (const float*)d_in[5];
  float* out = (float*)d_out;
  unsigned char* ws = (unsigned char*)d_ws;

  hipLaunchKernelGGL(sage_prep_kernel, dim3(2064), dim3(256), 0, stream,
                     x, Wself, Wnei, ws);
  hipLaunchKernelGGL(sage_fused_kernel, dim3(NBLK), dim3(256), 0, stream,
                     ws, adj, bself, bnei, out);
}

// Round 4
// 69.299 us; speedup vs baseline: 1.2427x; 1.2427x over previous
//
#include <hip/hip_runtime.h>
#include <hip/hip_bf16.h>

#define NBATCH 4
#define NNODE  20000
#define NF     128
#define NK     16
#define BM     32
#define NROWS  (NBATCH * NNODE)   // 80000
#define NBLK   (NROWS / BM)       // 2500
#define WTF_BYTES 65536           // 8c x 8s x 64lane x 16B fragment-permuted weights
#define XB16_OFF  WTF_BYTES       // bf16 x starts here in ws (20.48 MB)

typedef __attribute__((ext_vector_type(8))) short bf16x8_t;
typedef __attribute__((ext_vector_type(4))) float f32x4_t;

__device__ __forceinline__ unsigned short f2bf(float f) {
  unsigned int u = __float_as_uint(f);
  u += 0x7fffu + ((u >> 16) & 1u);
  return (unsigned short)(u >> 16);
}

// byte offset into sA: [row][512B], XOR-swizzled (both write & read sides)
__device__ __forceinline__ int swz(int row, int kbyte) {
  return (row << 9) + (kbyte ^ ((row & 31) << 4));
}

// ---------------- prep: x f32->bf16, weights -> fragment-permuted bf16 ----
__global__ __launch_bounds__(256) void sage_prep_kernel(
    const float* __restrict__ x, const float* __restrict__ Wself,
    const float* __restrict__ Wnei, unsigned char* __restrict__ ws)
{
  const int bid = blockIdx.x;
  const int tid = threadIdx.x;
  if (bid < 2048) {
    const float4* xv = reinterpret_cast<const float4*>(x);
    uint2* xb = reinterpret_cast<uint2*>(ws + XB16_OFF);
    const int total = NROWS * NF / 4;  // 2,560,000
    for (int c = bid * 256 + tid; c < total; c += 2048 * 256) {
      const float4 v = xv[c];
      uint2 p;
      p.x = (unsigned int)f2bf(v.x) | ((unsigned int)f2bf(v.y) << 16);
      p.y = (unsigned int)f2bf(v.z) | ((unsigned int)f2bf(v.w) << 16);
      xb[c] = p;
    }
  } else {
    // fragment-permuted stacked W^T: ft = (c*8+s)*64 + lane, 16B per ft
    const int ft = (bid - 2048) * 256 + tid;   // 0..4095
    const int c = ft >> 9;
    const int s = (ft >> 6) & 7;
    const int l = ft & 63;
    const int col = c * 16 + (l & 15);
    const int k0 = s * 32 + ((l >> 4) << 3);
    unsigned int w[4];
#pragma unroll
    for (int jj = 0; jj < 4; ++jj) {
      const int ka = k0 + jj * 2, kb = k0 + jj * 2 + 1;
      const float va = (ka < NF) ? Wself[ka * NF + col] : Wnei[(ka - NF) * NF + col];
      const float vb = (kb < NF) ? Wself[kb * NF + col] : Wnei[(kb - NF) * NF + col];
      w[jj] = (unsigned int)f2bf(va) | ((unsigned int)f2bf(vb) << 16);
    }
    *reinterpret_cast<uint4*>(ws + (size_t)ft * 16) = make_uint4(w[0], w[1], w[2], w[3]);
  }
}

// ---------------- fused gather + stacked GEMM ----------------------------
__global__ __launch_bounds__(256, 8) void sage_fused_kernel(
    const unsigned char* __restrict__ ws, const int* __restrict__ adj,
    const float* __restrict__ bself, const float* __restrict__ bnei,
    float* __restrict__ out)
{
  __shared__ __align__(16) unsigned char sA[BM * 512];  // 16 KB

  const int tid  = threadIdx.x;
  const int lane = tid & 63;
  const int wid  = tid >> 6;

  // bijective XCD-chunked swizzle: nwg=2500, q=312, r=4
  const int orig = blockIdx.x;
  const int xcd = orig & 7, i = orig >> 3;
  const int q = NBLK / 8, r = NBLK % 8;
  const int bid = (xcd < r ? xcd * (q + 1) : r * (q + 1) + (xcd - r) * q) + i;
  const int row0 = bid * BM;

  const unsigned char* xb16 = ws + XB16_OFF;

  // ---- stage x tile (k-bytes [0,256) of sA), coalesced 16B chunks
  {
    const int kb = (tid & 15) * 16;
#pragma unroll
    for (int it = 0; it < 2; ++it) {
      const int rr = it * 16 + (tid >> 4);
      const uint4 v = *reinterpret_cast<const uint4*>(
          xb16 + (size_t)(row0 + rr) * 256 + kb);
      *reinterpret_cast<uint4*>(sA + swz(rr, kb)) = v;
    }
  }

  // ---- gather + mean (k-bytes [256,512)): single pass, full 256B rows,
  //      8-deep explicit load pipeline (fits 64-VGPR cap -> 8 waves/SIMD)
  {
    const int fg   = (lane & 15) * 16;  // 16B chunk within the 256B row
    const int rsub = lane >> 4;         // 0..3
#pragma unroll
    for (int it = 0; it < 2; ++it) {
      const int rr = wid * 8 + it * 4 + rsub;
      const int gr = row0 + rr;
      const int b  = gr / NNODE;
      const unsigned char* xbb = xb16 + (size_t)b * NNODE * 256 + fg;
      const int4* a4 = reinterpret_cast<const int4*>(adj + (size_t)gr * NK);

      float a0=0,a1=0,a2=0,a3=0,a4f=0,a5=0,a6=0,a7=0;
      uint4 v[8];
#pragma unroll
      for (int half = 0; half < 2; ++half) {
        const int4 t0 = a4[half * 2 + 0];
        const int4 t1 = a4[half * 2 + 1];
        v[0] = *reinterpret_cast<const uint4*>(xbb + (size_t)t0.x * 256);
        v[1] = *reinterpret_cast<const uint4*>(xbb + (size_t)t0.y * 256);
        v[2] = *reinterpret_cast<const uint4*>(xbb + (size_t)t0.z * 256);
        v[3] = *reinterpret_cast<const uint4*>(xbb + (size_t)t0.w * 256);
        v[4] = *reinterpret_cast<const uint4*>(xbb + (size_t)t1.x * 256);
        v[5] = *reinterpret_cast<const uint4*>(xbb + (size_t)t1.y * 256);
        v[6] = *reinterpret_cast<const uint4*>(xbb + (size_t)t1.z * 256);
        v[7] = *reinterpret_cast<const uint4*>(xbb + (size_t)t1.w * 256);
#pragma unroll
        for (int k = 0; k < 8; ++k) {
          a0  += __uint_as_float(v[k].x << 16);
          a1  += __uint_as_float(v[k].x & 0xffff0000u);
          a2  += __uint_as_float(v[k].y << 16);
          a3  += __uint_as_float(v[k].y & 0xffff0000u);
          a4f += __uint_as_float(v[k].z << 16);
          a5  += __uint_as_float(v[k].z & 0xffff0000u);
          a6  += __uint_as_float(v[k].w << 16);
          a7  += __uint_as_float(v[k].w & 0xffff0000u);
        }
      }
      const float sc = 1.f / 16.f;
      uint4 p;
      p.x = (unsigned int)f2bf(a0*sc)  | ((unsigned int)f2bf(a1*sc) << 16);
      p.y = (unsigned int)f2bf(a2*sc)  | ((unsigned int)f2bf(a3*sc) << 16);
      p.z = (unsigned int)f2bf(a4f*sc) | ((unsigned int)f2bf(a5*sc) << 16);
      p.w = (unsigned int)f2bf(a6*sc)  | ((unsigned int)f2bf(a7*sc) << 16);
      *reinterpret_cast<uint4*>(sA + swz(rr, 256 + fg)) = p;
    }
  }

  __syncthreads();

  // ---- MFMA: wave w -> rows (w&1)*16..+16, cols (w>>1)*64..+64
  const int frow = lane & 15;
  const int kgrp = lane >> 4;
  const int mrow = (wid & 1) * 16;
  const int cb   = wid >> 1;

  f32x4_t acc[4];
#pragma unroll
  for (int c = 0; c < 4; ++c) acc[c] = (f32x4_t){0.f, 0.f, 0.f, 0.f};

  bf16x8_t afr[8];
#pragma unroll
  for (int s = 0; s < 8; ++s) {
    const int kb = s * 64 + kgrp * 16;
    afr[s] = *reinterpret_cast<const bf16x8_t*>(sA + swz(mrow + frow, kb));
  }

  const bf16x8_t* wtf = reinterpret_cast<const bf16x8_t*>(ws);
#pragma unroll
  for (int c = 0; c < 4; ++c) {
    const int gc = cb * 4 + c;
#pragma unroll
    for (int s = 0; s < 8; ++s) {
      const bf16x8_t bfr = wtf[(gc * 8 + s) * 64 + lane];
      acc[c] = __builtin_amdgcn_mfma_f32_16x16x32_bf16(afr[s], bfr, acc[c], 0, 0, 0);
    }
  }

  // ---- epilogue: bias + relu; C/D: col=lane&15, row=(lane>>4)*4+reg
#pragma unroll
  for (int c = 0; c < 4; ++c) {
    const int gc  = cb * 4 + c;
    const int col = gc * 16 + frow;
    const float bias = bself[col] + bnei[col];
#pragma unroll
    for (int j = 0; j < 4; ++j) {
      const int rr = mrow + kgrp * 4 + j;
      const float v = fmaxf(acc[c][j] + bias, 0.f);
      __builtin_nontemporal_store(v, &out[(size_t)(row0 + rr) * NF + col]);
    }
  }
}

extern "C" void kernel_launch(void* const* d_in, const int* in_sizes, int n_in,
                              void* d_out, int out_size, void* d_ws, size_t ws_size,
                              hipStream_t stream) {
  const float* x     = (const float*)d_in[0];
  const int*   adj   = (const int*)d_in[1];
  const float* Wself = (const float*)d_in[2];
  const float* bself = (const float*)d_in[3];
  const float* Wnei  = (const float*)d_in[4];
  const float* bnei  = (const float*)d_in[5];
  float* out = (float*)d_out;
  unsigned char* ws = (unsigned char*)d_ws;

  hipLaunchKernelGGL(sage_prep_kernel, dim3(2064), dim3(256), 0, stream,
                     x, Wself, Wnei, ws);
  hipLaunchKernelGGL(sage_fused_kernel, dim3(NBLK), dim3(256), 0, stream,
                     ws, adj, bself, bnei, out);
}

// Round 6
// 46.333 us; speedup vs baseline: 1.8588x; 1.4957x over previous
//
#include <hip/hip_runtime.h>
#include <hip/hip_bf16.h>

#define NBATCH 4
#define NNODE  20000
#define NF     128
#define NK     16
#define BM     64
#define NROWS  (NBATCH * NNODE)   // 80000
#define NBLK   (NROWS / BM)       // 1250
#define WTF_BYTES 65536           // 8c x 8s x 64lane x 16B fragment-permuted weights
#define XB16_OFF  WTF_BYTES                      // bf16 x copy (20.48 MB)
#define XF8_OFF   (XB16_OFF + NROWS * NF * 2)    // fp8 x copy (10.24 MB)

typedef __attribute__((ext_vector_type(8))) short bf16x8_t;
typedef __attribute__((ext_vector_type(4))) float f32x4_t;
typedef __attribute__((ext_vector_type(2))) float f32x2_t;

__device__ __forceinline__ unsigned int f2bf(float f) {
  unsigned int u = __float_as_uint(f);
  u += 0x7fffu + ((u >> 16) & 1u);
  return u >> 16;
}

// byte offset into sA: [row][512B], XOR-swizzled (both write & read sides)
__device__ __forceinline__ int swz(int row, int kbyte) {
  return (row << 9) + (kbyte ^ ((row & 31) << 4));
}

// ---------------- prep: x -> bf16 + fp8 copies, weights -> fragments -----
__global__ __launch_bounds__(256) void sage_prep_kernel(
    const float* __restrict__ x, const float* __restrict__ Wself,
    const float* __restrict__ Wnei, unsigned char* __restrict__ ws)
{
  const int bid = blockIdx.x;
  const int tid = threadIdx.x;
  if (bid < 2048) {
    const float4* xv = reinterpret_cast<const float4*>(x);
    uint2* xb = reinterpret_cast<uint2*>(ws + XB16_OFF);
    unsigned int* x8 = reinterpret_cast<unsigned int*>(ws + XF8_OFF);
    const int total = NROWS * NF / 4;  // 2,560,000 float4 chunks
    for (int c = bid * 256 + tid; c < total; c += 2048 * 256) {
      const float4 v = xv[c];
      uint2 p;
      p.x = f2bf(v.x) | (f2bf(v.y) << 16);
      p.y = f2bf(v.z) | (f2bf(v.w) << 16);
      xb[c] = p;
      int p8 = 0;
      p8 = __builtin_amdgcn_cvt_pk_fp8_f32(v.x, v.y, p8, false);
      p8 = __builtin_amdgcn_cvt_pk_fp8_f32(v.z, v.w, p8, true);
      x8[c] = (unsigned int)p8;
    }
  } else {
    // fragment-permuted stacked W^T: ft = (c*8+s)*64 + lane, 16B per ft
    const int ft = (bid - 2048) * 256 + tid;   // 0..4095
    const int c = ft >> 9;
    const int s = (ft >> 6) & 7;
    const int l = ft & 63;
    const int col = c * 16 + (l & 15);
    const int k0 = s * 32 + ((l >> 4) << 3);
    unsigned int w[4];
#pragma unroll
    for (int jj = 0; jj < 4; ++jj) {
      const int ka = k0 + jj * 2, kb = k0 + jj * 2 + 1;
      const float va = (ka < NF) ? Wself[ka * NF + col] : Wnei[(ka - NF) * NF + col];
      const float vb = (kb < NF) ? Wself[kb * NF + col] : Wnei[(kb - NF) * NF + col];
      w[jj] = f2bf(va) | (f2bf(vb) << 16);
    }
    *reinterpret_cast<uint4*>(ws + (size_t)ft * 16) = make_uint4(w[0], w[1], w[2], w[3]);
  }
}

// ---------------- fused gather + stacked GEMM ----------------------------
__global__ __launch_bounds__(256) void sage_fused_kernel(
    const unsigned char* __restrict__ ws, const int* __restrict__ adj,
    const float* __restrict__ bself, const float* __restrict__ bnei,
    float* __restrict__ out)
{
  __shared__ __align__(16) unsigned char sA[BM * 512];  // 32 KB

  const int tid  = threadIdx.x;
  const int lane = tid & 63;
  const int wid  = tid >> 6;

  // bijective XCD-chunked swizzle: nwg=1250, q=156, r=2
  const int orig = blockIdx.x;
  const int xcd = orig & 7, i = orig >> 3;
  const int q = NBLK / 8, r = NBLK % 8;
  const int bid = (xcd < r ? xcd * (q + 1) : r * (q + 1) + (xcd - r) * q) + i;
  const int row0 = bid * BM;

  const unsigned char* xb16 = ws + XB16_OFF;
  const unsigned char* xf8  = ws + XF8_OFF;

  // ---- stage x tile (k-bytes [0,256) of sA) from bf16 copy, 16B chunks
  {
    const int kb = (tid & 15) * 16;
#pragma unroll
    for (int it = 0; it < 4; ++it) {
      const int rr = it * 16 + (tid >> 4);
      const uint4 v = *reinterpret_cast<const uint4*>(
          xb16 + (size_t)(row0 + rr) * 256 + kb);
      *reinterpret_cast<uint4*>(sA + swz(rr, kb)) = v;
    }
  }

  // ---- gather + mean from fp8 copy (k-bytes [256,512) of sA)
  // 8 lanes x 16B cover a 128B fp8 row; wave does 8 rows/pass, 2 passes
  {
    const int fg   = (lane & 7) * 16;   // fp8 byte (== feature) offset
    const int rsub = lane >> 3;         // 0..7
#pragma unroll
    for (int pass = 0; pass < 2; ++pass) {
      const int rr = wid * 16 + pass * 8 + rsub;
      const int gr = row0 + rr;
      const int b  = gr / NNODE;
      const unsigned char* xbb = xf8 + (size_t)b * NNODE * 128 + fg;
      const int4* a4 = reinterpret_cast<const int4*>(adj + (size_t)gr * NK);

      float acc16[16];
#pragma unroll
      for (int k = 0; k < 16; ++k) acc16[k] = 0.f;

#pragma unroll
      for (int half = 0; half < 2; ++half) {
        const int4 t0 = a4[half * 2 + 0];
        const int4 t1 = a4[half * 2 + 1];
        uint4 v[8];
        v[0] = *reinterpret_cast<const uint4*>(xbb + (size_t)t0.x * 128);
        v[1] = *reinterpret_cast<const uint4*>(xbb + (size_t)t0.y * 128);
        v[2] = *reinterpret_cast<const uint4*>(xbb + (size_t)t0.z * 128);
        v[3] = *reinterpret_cast<const uint4*>(xbb + (size_t)t0.w * 128);
        v[4] = *reinterpret_cast<const uint4*>(xbb + (size_t)t1.x * 128);
        v[5] = *reinterpret_cast<const uint4*>(xbb + (size_t)t1.y * 128);
        v[6] = *reinterpret_cast<const uint4*>(xbb + (size_t)t1.z * 128);
        v[7] = *reinterpret_cast<const uint4*>(xbb + (size_t)t1.w * 128);
#define UNPK(word, base)                                                  \
        {                                                                 \
          f32x2_t lo = __builtin_amdgcn_cvt_pk_f32_fp8((word), false);    \
          f32x2_t hi = __builtin_amdgcn_cvt_pk_f32_fp8((word), true);     \
          acc16[(base) + 0] += lo[0]; acc16[(base) + 1] += lo[1];         \
          acc16[(base) + 2] += hi[0]; acc16[(base) + 3] += hi[1];         \
        }
#pragma unroll
        for (int k = 0; k < 8; ++k) {
          UNPK(v[k].x, 0)
          UNPK(v[k].y, 4)
          UNPK(v[k].z, 8)
          UNPK(v[k].w, 12)
        }
#undef UNPK
      }
      const float sc = 1.f / 16.f;
      uint4 p0, p1;
      p0.x = f2bf(acc16[0]*sc)  | (f2bf(acc16[1]*sc)  << 16);
      p0.y = f2bf(acc16[2]*sc)  | (f2bf(acc16[3]*sc)  << 16);
      p0.z = f2bf(acc16[4]*sc)  | (f2bf(acc16[5]*sc)  << 16);
      p0.w = f2bf(acc16[6]*sc)  | (f2bf(acc16[7]*sc)  << 16);
      p1.x = f2bf(acc16[8]*sc)  | (f2bf(acc16[9]*sc)  << 16);
      p1.y = f2bf(acc16[10]*sc) | (f2bf(acc16[11]*sc) << 16);
      p1.z = f2bf(acc16[12]*sc) | (f2bf(acc16[13]*sc) << 16);
      p1.w = f2bf(acc16[14]*sc) | (f2bf(acc16[15]*sc) << 16);
      const int kb = 256 + fg * 2;   // bf16 side: 2B per feature
      *reinterpret_cast<uint4*>(sA + swz(rr, kb))      = p0;
      *reinterpret_cast<uint4*>(sA + swz(rr, kb + 16)) = p1;
    }
  }

  __syncthreads();

  // ---- MFMA: wave wid -> rows [16*wid,16*wid+16) x 128 cols
  const int frow = lane & 15;
  const int kgrp = lane >> 4;

  f32x4_t acc[8];
#pragma unroll
  for (int c = 0; c < 8; ++c) acc[c] = (f32x4_t){0.f, 0.f, 0.f, 0.f};

  bf16x8_t afr[8];
#pragma unroll
  for (int s = 0; s < 8; ++s) {
    const int kb = s * 64 + kgrp * 16;
    afr[s] = *reinterpret_cast<const bf16x8_t*>(sA + swz(wid * 16 + frow, kb));
  }

  const bf16x8_t* wtf = reinterpret_cast<const bf16x8_t*>(ws);
#pragma unroll
  for (int c = 0; c < 8; ++c) {
#pragma unroll
    for (int s = 0; s < 8; ++s) {
      const bf16x8_t bfr = wtf[(c * 8 + s) * 64 + lane];
      acc[c] = __builtin_amdgcn_mfma_f32_16x16x32_bf16(afr[s], bfr, acc[c], 0, 0, 0);
    }
  }

  // ---- epilogue: bias + relu; C/D: col=lane&15, row=(lane>>4)*4+reg
#pragma unroll
  for (int c = 0; c < 8; ++c) {
    const int col  = c * 16 + frow;
    const float bias = bself[col] + bnei[col];
#pragma unroll
    for (int j = 0; j < 4; ++j) {
      const int rr = wid * 16 + kgrp * 4 + j;
      const float v = acc[c][j] + bias;
      out[(size_t)(row0 + rr) * NF + col] = fmaxf(v, 0.f);
    }
  }
}

extern "C" void kernel_launch(void* const* d_in, const int* in_sizes, int n_in,
                              void* d_out, int out_size, void* d_ws, size_t ws_size,
                              hipStream_t stream) {
  const float* x     = (const float*)d_in[0];
  const int*   adj   = (const int*)d_in[1];
  const float* Wself = (const float*)d_in[2];
  const float* bself = (const float*)d_in[3];
  const float* Wnei  = (const float*)d_in[4];
  const float* bnei  = (const float*)d_in[5];
  float* out = (float*)d_out;
  unsigned char* ws = (unsigned char*)d_ws;

  hipLaunchKernelGGL(sage_prep_kernel, dim3(2064), dim3(256), 0, stream,
                     x, Wself, Wnei, ws);
  hipLaunchKernelGGL(sage_fused_kernel, dim3(NBLK), dim3(256), 0, stream,
                     ws, adj, bself, bnei, out);
}